// Round 2
// baseline (174.056 us; speedup 1.0000x reference)
//
#include <hip/hip_runtime.h>

typedef __bf16 v8bf  __attribute__((ext_vector_type(8)));
typedef __bf16 v4bf  __attribute__((ext_vector_type(4)));
typedef float  f32x4  __attribute__((ext_vector_type(4)));
typedef float  f32x16 __attribute__((ext_vector_type(16)));

#define NI   31        // number of per-dim nets (D-1)
#define DD   32        // input dim
#define NHID 128       // hidden width
#define BT   128       // batch tile per block
#define NBT  256       // 32768 / BT

// ---------------- prep: transpose + bf16-convert weights into ws ----------------
__global__ void maf_prep(const float* __restrict__ W1, const float* __restrict__ W2,
                         const float* __restrict__ W3,
                         __bf16* __restrict__ WT2, __bf16* __restrict__ WT3,
                         __bf16* __restrict__ WT1) {
    int b = blockIdx.x, t = threadIdx.x;
    if (b < 2 * NI) {                 // W2/W3: [kin][fo] -> [fo][kin]
        int i = b % NI;
        const float* src = (b < NI ? W2 : W3) + (size_t)i * NHID * NHID;
        __bf16* dst = (b < NI ? WT2 : WT3) + (size_t)i * NHID * NHID;
        for (int j = 0; j < 64; ++j) {
            int e = j * 256 + t;
            int fo = e >> 7, kin = e & 127;
            dst[e] = (__bf16)src[kin * NHID + fo];
        }
    } else {                          // W1: [d][fo] -> [fo][d]
        int i = b - 2 * NI;
        const float* src = W1 + (size_t)i * DD * NHID;
        __bf16* dst = WT1 + (size_t)i * NHID * DD;
        for (int j = 0; j < 16; ++j) {
            int e = j * 256 + t;
            int fo = e >> 5, d = e & 31;
            dst[e] = (__bf16)src[d * NHID + fo];
        }
    }
}

// ---------------- init: z[:,0], log_det = p0.s ----------------
__global__ void maf_init(const float* __restrict__ x, const float* __restrict__ p0,
                         float* __restrict__ zout, float* __restrict__ ldout) {
    int row = blockIdx.x * 256 + threadIdx.x;     // 0..32767
    float s = p0[0], tt = p0[1];
    ldout[row] = s;
    zout[(size_t)row * DD] = x[(size_t)row * DD] * expf(s) + tt;
}

// swizzled hbuf byte offset: row stride 256B, 16B slots XORed by (batch&15)
#define HADDR(batch, blk)  ((batch) * 256 + ((((blk) ^ ((batch) & 15))) << 4))

// ---------------- main fused kernel ----------------
__global__ __launch_bounds__(256, 4) void maf_main(
    const float* __restrict__ x,
    const __bf16* __restrict__ WT1, const __bf16* __restrict__ WT2,
    const __bf16* __restrict__ WT3,
    const float* __restrict__ b1, const float* __restrict__ b2,
    const float* __restrict__ b3,
    const float* __restrict__ W4, const float* __restrict__ b4,
    float* __restrict__ zout, float* __restrict__ ldout) {

    __shared__ __align__(16) __bf16 hbuf_s[NHID * BT];   // 32 KB, swizzled
    __shared__ __align__(16) float  bsm[3 * NHID];       // b1|b2|b3
    __shared__ __align__(16) __bf16 w4t[2 * NHID];       // W4^T, [2][128]

    char* hb = (char*)hbuf_s;

    const int t   = threadIdx.x;
    const int i   = blockIdx.x >> 8;          // net 0..30
    const int bt  = blockIdx.x & 255;         // batch tile
    const int l   = t & 63;
    const int w   = t >> 6;                   // wave 0..3
    const int c32 = l & 31;
    const int hi  = l >> 5;
    const int wr  = w >> 1;                   // feat half
    const int wc  = w & 1;                    // batch half
    const int sxr = c32 & 15;                 // swizzle key (== batch&15 everywhere below)

    // stage biases + W4^T (tiny)
    if (t < NHID) {
        bsm[t]            = b1[i * NHID + t];
        bsm[NHID + t]     = b2[i * NHID + t];
        bsm[2 * NHID + t] = b3[i * NHID + t];
    }
    w4t[t] = (__bf16)W4[(size_t)i * 2 * NHID + (t & 127) * 2 + (t >> 7)];

    f32x16 acc[2][2];

    // ================= layer 1: h1^T = W1^T(128x32) * x^T =================
    {
        const __bf16* wbase = WT1 + (size_t)i * NHID * DD;
        v8bf af[2][2], bf[2][2];
        #pragma unroll
        for (int mt = 0; mt < 2; ++mt)
            #pragma unroll
            for (int ks = 0; ks < 2; ++ks)
                af[mt][ks] = *(const v8bf*)&wbase[(wr * 64 + mt * 32 + c32) * DD + ks * 16 + hi * 8];
        #pragma unroll
        for (int nt = 0; nt < 2; ++nt)
            #pragma unroll
            for (int ks = 0; ks < 2; ++ks) {
                const float* xp = x + (size_t)(bt * BT + wc * 64 + nt * 32 + c32) * DD + ks * 16 + hi * 8;
                f32x4 x0 = *(const f32x4*)xp;
                f32x4 x1 = *(const f32x4*)(xp + 4);
                v8bf bv;
                #pragma unroll
                for (int j = 0; j < 4; ++j) { bv[j] = (__bf16)x0[j]; bv[j + 4] = (__bf16)x1[j]; }
                bf[nt][ks] = bv;
            }
        #pragma unroll
        for (int mt = 0; mt < 2; ++mt)
            #pragma unroll
            for (int nt = 0; nt < 2; ++nt) {
                f32x16 a = {0.f,0.f,0.f,0.f,0.f,0.f,0.f,0.f,0.f,0.f,0.f,0.f,0.f,0.f,0.f,0.f};
                a = __builtin_amdgcn_mfma_f32_32x32x16_bf16(af[mt][0], bf[nt][0], a, 0, 0, 0);
                a = __builtin_amdgcn_mfma_f32_32x32x16_bf16(af[mt][1], bf[nt][1], a, 0, 0, 0);
                acc[mt][nt] = a;
            }
    }
    __syncthreads();   // bsm/w4t staged; hbuf untouched so writes below are safe

    // epilogue macro: bias + leaky-relu + bf16 pack + swizzled b64 store
#define EPILOGUE(L)                                                                     \
    {                                                                                   \
        const float* bb = bsm + (L) * NHID + wr * 64;                                   \
        _Pragma("unroll")                                                               \
        for (int mt = 0; mt < 2; ++mt)                                                  \
            _Pragma("unroll")                                                           \
            for (int q = 0; q < 4; ++q) {                                               \
                f32x4 bv = *(const f32x4*)&bb[mt * 32 + q * 8 + hi * 4];                \
                int sw = (((wr * 8 + mt * 4 + q) ^ sxr) << 4) + hi * 8;                 \
                _Pragma("unroll")                                                       \
                for (int nt = 0; nt < 2; ++nt) {                                        \
                    int batch = wc * 64 + nt * 32 + c32;                                \
                    v4bf pk;                                                            \
                    _Pragma("unroll")                                                   \
                    for (int j = 0; j < 4; ++j) {                                       \
                        float v = acc[mt][nt][q * 4 + j] + bv[j];                       \
                        v = fmaxf(v, 0.2f * v);                                         \
                        pk[j] = (__bf16)v;                                              \
                    }                                                                   \
                    *(v4bf*)(hb + batch * 256 + sw) = pk;                               \
                }                                                                       \
            }                                                                           \
    }

    // hidden layer macro: acc = W^T * h (A from global, B from swizzled hbuf)
#define LAYER(WTP)                                                                      \
    {                                                                                   \
        const __bf16* wbase = (WTP) + (size_t)i * NHID * NHID;                          \
        _Pragma("unroll")                                                               \
        for (int mt = 0; mt < 2; ++mt)                                                  \
            _Pragma("unroll")                                                           \
            for (int nt = 0; nt < 2; ++nt)                                              \
                acc[mt][nt] = (f32x16){0.f,0.f,0.f,0.f,0.f,0.f,0.f,0.f,                 \
                                       0.f,0.f,0.f,0.f,0.f,0.f,0.f,0.f};               \
        _Pragma("unroll")                                                               \
        for (int ks = 0; ks < 8; ++ks) {                                                \
            v8bf a0 = *(const v8bf*)&wbase[(wr * 64 + c32) * NHID + ks * 16 + hi * 8];  \
            v8bf a1 = *(const v8bf*)&wbase[(wr * 64 + 32 + c32) * NHID + ks * 16 + hi * 8]; \
            int kb = ((ks * 2 + hi) ^ sxr) << 4;                                        \
            v8bf b0 = *(const v8bf*)(hb + (wc * 64 + c32) * 256 + kb);                  \
            v8bf b1v = *(const v8bf*)(hb + (wc * 64 + 32 + c32) * 256 + kb);            \
            acc[0][0] = __builtin_amdgcn_mfma_f32_32x32x16_bf16(a0, b0,  acc[0][0], 0, 0, 0); \
            acc[0][1] = __builtin_amdgcn_mfma_f32_32x32x16_bf16(a0, b1v, acc[0][1], 0, 0, 0); \
            acc[1][0] = __builtin_amdgcn_mfma_f32_32x32x16_bf16(a1, b0,  acc[1][0], 0, 0, 0); \
            acc[1][1] = __builtin_amdgcn_mfma_f32_32x32x16_bf16(a1, b1v, acc[1][1], 0, 0, 0); \
        }                                                                               \
    }

    EPILOGUE(0)        // write h1
    __syncthreads();
    LAYER(WT2)         // read h1
    __syncthreads();
    EPILOGUE(1)        // write h2
    __syncthreads();
    LAYER(WT3)         // read h2
    __syncthreads();
    EPILOGUE(2)        // write h3
    __syncthreads();

    // ================= layer 4 via one padded MFMA strip =================
    {
        f32x16 a4c = {0.f,0.f,0.f,0.f,0.f,0.f,0.f,0.f,0.f,0.f,0.f,0.f,0.f,0.f,0.f,0.f};
        int batch = w * 32 + c32;             // each wave owns 32 batches
        int sb = batch & 15;
        #pragma unroll
        for (int ks = 0; ks < 8; ++ks) {
            v8bf av = {};
            if (c32 < 2)                       // A rows >=2 are zero -> ignored C rows
                av = *(const v8bf*)&w4t[c32 * NHID + ks * 16 + hi * 8];
            v8bf bv = *(const v8bf*)(hb + batch * 256 + (((ks * 2 + hi) ^ sb) << 4));
            a4c = __builtin_amdgcn_mfma_f32_32x32x16_bf16(av, bv, a4c, 0, 0, 0);
        }
        if (l < 32) {                          // hi==0 lanes hold rows 0(s),1(t)
            int row = bt * BT + batch;
            float s  = a4c[0] + b4[2 * i];
            float tt = a4c[1] + b4[2 * i + 1];
            float xv = x[(size_t)row * DD + i + 1];
            zout[(size_t)row * DD + i + 1] = xv * expf(s) + tt;
            atomicAdd(&ldout[row], s);
        }
    }
#undef EPILOGUE
#undef LAYER
}

extern "C" void kernel_launch(void* const* d_in, const int* in_sizes, int n_in,
                              void* d_out, int out_size, void* d_ws, size_t ws_size,
                              hipStream_t stream) {
    (void)in_sizes; (void)n_in; (void)out_size; (void)ws_size;
    const float* x  = (const float*)d_in[0];
    const float* p0 = (const float*)d_in[1];
    const float* W1 = (const float*)d_in[2];
    const float* b1 = (const float*)d_in[3];
    const float* W2 = (const float*)d_in[4];
    const float* b2 = (const float*)d_in[5];
    const float* W3 = (const float*)d_in[6];
    const float* b3 = (const float*)d_in[7];
    const float* W4 = (const float*)d_in[8];
    const float* b4 = (const float*)d_in[9];

    float* zout  = (float*)d_out;
    float* ldout = zout + (size_t)32768 * DD;

    __bf16* WT2 = (__bf16*)d_ws;                    // [31][128][128]
    __bf16* WT3 = WT2 + (size_t)NI * NHID * NHID;   // [31][128][128]
    __bf16* WT1 = WT3 + (size_t)NI * NHID * NHID;   // [31][128][32]

    maf_prep<<<3 * NI, 256, 0, stream>>>(W1, W2, W3, WT2, WT3, WT1);
    maf_init<<<32768 / 256, 256, 0, stream>>>(x, p0, zout, ldout);
    maf_main<<<NI * NBT, 256, 0, stream>>>(x, WT1, WT2, WT3,
                                           b1, b2, b3, W4, b4, zout, ldout);
}